// Round 4
// baseline (528.843 us; speedup 1.0000x reference)
//
#include <hip/hip_runtime.h>
#include <hip/hip_bf16.h>

#define S_LEN 2048
#define DM 1024
#define NH 16
#define DH 64
#define MTOK 4096
#define NC 4
#define CHUNK 512

typedef __attribute__((ext_vector_type(8))) __bf16 bf16x8;
typedef __attribute__((ext_vector_type(4))) float f32x4;
typedef unsigned short u16;
typedef unsigned long long u64;

__device__ __forceinline__ u16 f2bf(float f) {
  union { float f; unsigned u; } a; a.f = f;
  unsigned u = a.u;
  u += 0x7fffu + ((u >> 16) & 1u);   // RNE
  return (u16)(u >> 16);
}

__device__ __forceinline__ bf16x8 ld_bf8(const u16* p) {
  return *reinterpret_cast<const bf16x8*>(p);
}

// ---------------- fp32 -> bf16 convert ----------------
__global__ void k_convert(const float* __restrict__ src, u16* __restrict__ dst, int n4) {
  int i = blockIdx.x * blockDim.x + threadIdx.x;
  int stride = gridDim.x * blockDim.x;
  for (; i < n4; i += stride) {
    float4 v = reinterpret_cast<const float4*>(src)[i];
    ushort4 o;
    o.x = f2bf(v.x); o.y = f2bf(v.y); o.z = f2bf(v.z); o.w = f2bf(v.w);
    reinterpret_cast<ushort4*>(dst)[i] = o;
  }
}

// ---------------- mask bit-pack: [B][S][S] i32 -> [B][S][S/64] u64 ----------------
__global__ void k_maskpack(const int* __restrict__ m, u64* __restrict__ o, int n) {
  int i = blockIdx.x * blockDim.x + threadIdx.x;
  int stride = gridDim.x * blockDim.x;
  for (; i < n; i += stride) {
    u64 bal = __ballot(m[i] != 0);   // bit l = lane l's col (i aligned to 64 per wave)
    if ((i & 63) == 0) o[i >> 6] = bal;
  }
}

// ---------------- bf16 GEMM, B^T weights: C = A @ W^T + bias ----------------
// A [M=4096][K=1024] bf16 row-major, Bw [N=1024][K=1024] bf16 row-major.
// MODE 0: bf16 out scattered to [B*H][S][DH]   (Q, K buffers)
// MODE 1: bf16 out scattered to [B*H][DH][S]   (V transposed)
// MODE 2: f32 out row-major [M][N]             (final output)
template<int MODE>
__global__ __launch_bounds__(256) void k_gemm(
    const u16* __restrict__ A, const u16* __restrict__ Bw,
    const float* __restrict__ bias, void* __restrict__ dst) {
  constexpr int K = DM;
  __shared__ u16 As[128 * 32];
  __shared__ u16 Bs[128 * 32];
  const int tid = threadIdx.x;
  const int lane = tid & 63;
  const int wid = tid >> 6;
  const int wm = wid >> 1, wn = wid & 1;
  const int bm = blockIdx.x * 128;
  const int bn = blockIdx.y * 128;
  const int r0 = tid >> 2;           // 0..63
  const int c0 = (tid & 3) * 8;      // bf16 offset within 32-wide row
  const int fr = lane & 15;
  const int fk = (lane >> 4) * 8;

  f32x4 acc[4][4] = {};

  const u16* ga = A + (size_t)(bm + r0) * K + c0;
  const u16* gb = Bw + (size_t)(bn + r0) * K + c0;

  for (int kt = 0; kt < K; kt += 32) {
    __syncthreads();
    __builtin_amdgcn_global_load_lds(
        (const __attribute__((address_space(1))) void*)(ga + kt),
        (__attribute__((address_space(3))) void*)(&As[r0 * 32 + c0]), 16, 0, 0);
    __builtin_amdgcn_global_load_lds(
        (const __attribute__((address_space(1))) void*)(ga + (size_t)64 * K + kt),
        (__attribute__((address_space(3))) void*)(&As[(r0 + 64) * 32 + c0]), 16, 0, 0);
    __builtin_amdgcn_global_load_lds(
        (const __attribute__((address_space(1))) void*)(gb + kt),
        (__attribute__((address_space(3))) void*)(&Bs[r0 * 32 + c0]), 16, 0, 0);
    __builtin_amdgcn_global_load_lds(
        (const __attribute__((address_space(1))) void*)(gb + (size_t)64 * K + kt),
        (__attribute__((address_space(3))) void*)(&Bs[(r0 + 64) * 32 + c0]), 16, 0, 0);
    __syncthreads();
    bf16x8 af[4], bfr[4];
#pragma unroll
    for (int m = 0; m < 4; ++m) af[m] = ld_bf8(&As[(wm * 64 + m * 16 + fr) * 32 + fk]);
#pragma unroll
    for (int n = 0; n < 4; ++n) bfr[n] = ld_bf8(&Bs[(wn * 64 + n * 16 + fr) * 32 + fk]);
#pragma unroll
    for (int m = 0; m < 4; ++m)
#pragma unroll
      for (int n = 0; n < 4; ++n)
        acc[m][n] = __builtin_amdgcn_mfma_f32_16x16x32_bf16(af[m], bfr[n], acc[m][n], 0, 0, 0);
  }

  // C/D layout: col = lane&15, row = (lane>>4)*4 + reg
  const int cr = (lane >> 4) * 4;
  const int cc = lane & 15;
#pragma unroll
  for (int m = 0; m < 4; ++m) {
#pragma unroll
    for (int n = 0; n < 4; ++n) {
      const int colg = bn + wn * 64 + n * 16 + cc;
      const float bv = bias[colg];
      const int rbase = bm + wm * 64 + m * 16 + cr;
      if (MODE == 2) {
        float* o = (float*)dst;
#pragma unroll
        for (int r = 0; r < 4; ++r)
          o[(size_t)(rbase + r) * DM + colg] = acc[m][n][r] + bv;
      } else if (MODE == 0) {
        u16* o = (u16*)dst;
        const int h = colg >> 6, d = colg & 63;
#pragma unroll
        for (int r = 0; r < 4; ++r) {
          const int tok = rbase + r;
          const int b = tok >> 11, s = tok & 2047;
          o[(((size_t)(b * NH + h) * S_LEN) + s) * DH + d] = f2bf(acc[m][n][r] + bv);
        }
      } else {
        u16* o = (u16*)dst;
        const int h = colg >> 6, d = colg & 63;
        const int tok = rbase;
        const int b = tok >> 11, s = tok & 2047;
        ushort4 pk;
        pk.x = f2bf(acc[m][n][0] + bv);
        pk.y = f2bf(acc[m][n][1] + bv);
        pk.z = f2bf(acc[m][n][2] + bv);
        pk.w = f2bf(acc[m][n][3] + bv);
        *reinterpret_cast<ushort4*>(&o[(((size_t)(b * NH + h) * DH) + d) * S_LEN + s]) = pk;
      }
    }
  }
}

// ---------------- fused flash attention, chunked over kt for TLP ----------------
// Each block: (qt, h, chunk) — processes kt in [chunk*512, chunk*512+512) for both
// batches, writes unnormalized partials (ctx f32, m, l) for the combine kernel.
// Qb,Kb: [B*H][S][64] bf16; Vt: [B*H][64][S] bf16; bias [H][S][S] f32;
// mpk [B][S][32] u64; ctxp [NC*B][H][S][64] f32; mlp [NC*B][H][S][2] f32
__global__ __launch_bounds__(256, 4) void k_attn(
    const u16* __restrict__ Qb, const u16* __restrict__ Kb, const u16* __restrict__ Vt,
    const float* __restrict__ bias, const u64* __restrict__ mpk,
    float* __restrict__ ctxp, float* __restrict__ mlp) {
  __shared__ u16 P[4][16][72];   // per-wave P tile (no block barrier needed)
  const int tid = threadIdx.x;
  const int lane = tid & 63;
  const int w = tid >> 6;
  const int qt = blockIdx.x;
  const int h = blockIdx.y;
  const int chunk = blockIdx.z;
  const int fr = lane & 15;
  const int fk = (lane >> 4) * 8;
  const int cr = (lane >> 4) * 4;
  const int cc = lane & 15;
  const int q0 = qt * 64 + w * 16;

  const float* bp = bias + (size_t)h * S_LEN * S_LEN;

  bf16x8 qf[2][2];
  f32x4 cacc[2][4] = {};
  float m_run[2][4], l_run[2][4];
#pragma unroll
  for (int b = 0; b < 2; ++b) {
    const u16* Qp = Qb + (size_t)(b * NH + h) * S_LEN * DH;
    qf[b][0] = ld_bf8(&Qp[(size_t)(q0 + fr) * DH + fk]);
    qf[b][1] = ld_bf8(&Qp[(size_t)(q0 + fr) * DH + 32 + fk]);
#pragma unroll
    for (int r = 0; r < 4; ++r) { m_run[b][r] = -1e30f; l_run[b][r] = 0.f; }
  }

  const int kt_lo = chunk * CHUNK;
  const int kt_hi = kt_lo + CHUNK;
  for (int kt = kt_lo; kt < kt_hi; kt += 64) {
    // ---- bias tile into registers, read ONCE, shared across both batches ----
    float bv[4][4];
#pragma unroll
    for (int nb = 0; nb < 4; ++nb)
#pragma unroll
      for (int r = 0; r < 4; ++r)
        bv[nb][r] = bp[(size_t)(q0 + cr + r) * S_LEN + kt + nb * 16 + cc];
    // ---- packed mask words (broadcast loads, L2-resident) ----
    u64 mw[2][4];
#pragma unroll
    for (int b = 0; b < 2; ++b)
#pragma unroll
      for (int r = 0; r < 4; ++r)
        mw[b][r] = mpk[((size_t)b * S_LEN + q0 + cr + r) * 32 + (kt >> 6)];

#pragma unroll
    for (int b = 0; b < 2; ++b) {
      const u16* Kp = Kb + (size_t)(b * NH + h) * S_LEN * DH;
      const u16* Vp = Vt + (size_t)(b * NH + h) * DH * S_LEN;
      // ---- scores = Q K^T ----
      f32x4 sc[4] = {};
#pragma unroll
      for (int nb = 0; nb < 4; ++nb) {
        bf16x8 kf0 = ld_bf8(&Kp[(size_t)(kt + nb * 16 + fr) * DH + fk]);
        bf16x8 kf1 = ld_bf8(&Kp[(size_t)(kt + nb * 16 + fr) * DH + 32 + fk]);
        sc[nb] = __builtin_amdgcn_mfma_f32_16x16x32_bf16(qf[b][0], kf0, sc[nb], 0, 0, 0);
        sc[nb] = __builtin_amdgcn_mfma_f32_16x16x32_bf16(qf[b][1], kf1, sc[nb], 0, 0, 0);
      }
      // ---- scale + bias + mask ----
#pragma unroll
      for (int nb = 0; nb < 4; ++nb)
#pragma unroll
        for (int r = 0; r < 4; ++r) {
          const float val = sc[nb][r] * 0.125f + bv[nb][r];
          sc[nb][r] = ((mw[b][r] >> (nb * 16 + cc)) & 1) ? val : -1e9f;
        }
      // ---- online softmax (row split across lane bits 0..3) ----
#pragma unroll
      for (int r = 0; r < 4; ++r) {
        float v = fmaxf(fmaxf(sc[0][r], sc[1][r]), fmaxf(sc[2][r], sc[3][r]));
        v = fmaxf(v, __shfl_xor(v, 1));
        v = fmaxf(v, __shfl_xor(v, 2));
        v = fmaxf(v, __shfl_xor(v, 4));
        v = fmaxf(v, __shfl_xor(v, 8));
        const float mn = fmaxf(m_run[b][r], v);
        const float corr = __expf(m_run[b][r] - mn);
        m_run[b][r] = mn;
        l_run[b][r] *= corr;
        cacc[b][0][r] *= corr; cacc[b][1][r] *= corr;
        cacc[b][2][r] *= corr; cacc[b][3][r] *= corr;
        float s0 = 0.f;
#pragma unroll
        for (int nb = 0; nb < 4; ++nb) {
          const float p = __expf(sc[nb][r] - mn);
          sc[nb][r] = p;
          s0 += p;
        }
        s0 += __shfl_xor(s0, 1);
        s0 += __shfl_xor(s0, 2);
        s0 += __shfl_xor(s0, 4);
        s0 += __shfl_xor(s0, 8);
        l_run[b][r] += s0;
      }
      // ---- P -> LDS relayout (per-wave tile, wave-internal ordering only) ----
#pragma unroll
      for (int nb = 0; nb < 4; ++nb)
#pragma unroll
        for (int r = 0; r < 4; ++r)
          P[w][cr + r][nb * 16 + cc] = f2bf(sc[nb][r]);
      bf16x8 pf0 = ld_bf8(&P[w][fr][fk]);
      bf16x8 pf1 = ld_bf8(&P[w][fr][32 + fk]);
      // ---- ctx += P V ----
#pragma unroll
      for (int nd = 0; nd < 4; ++nd) {
        bf16x8 vf0 = ld_bf8(&Vp[(size_t)(nd * 16 + fr) * S_LEN + kt + fk]);
        bf16x8 vf1 = ld_bf8(&Vp[(size_t)(nd * 16 + fr) * S_LEN + kt + 32 + fk]);
        cacc[b][nd] = __builtin_amdgcn_mfma_f32_16x16x32_bf16(pf0, vf0, cacc[b][nd], 0, 0, 0);
        cacc[b][nd] = __builtin_amdgcn_mfma_f32_16x16x32_bf16(pf1, vf1, cacc[b][nd], 0, 0, 0);
      }
    }
  }
  // ---- epilogue: write unnormalized partials ----
#pragma unroll
  for (int b = 0; b < 2; ++b)
#pragma unroll
    for (int r = 0; r < 4; ++r) {
      const size_t base = ((size_t)(chunk * 2 + b) * NH + h) * S_LEN + (q0 + cr + r);
      mlp[base * 2]     = m_run[b][r];   // 16 lanes write same value — benign
      mlp[base * 2 + 1] = l_run[b][r];
#pragma unroll
      for (int nd = 0; nd < 4; ++nd)
        ctxp[base * DH + nd * 16 + cc] = cacc[b][nd][r];
    }
}

// ---------------- combine partials: log-sum-exp merge over NC chunks ----------------
__global__ __launch_bounds__(256) void k_combine(
    const float* __restrict__ ctxp, const float* __restrict__ mlp,
    u16* __restrict__ ctx) {
  const int idx = blockIdx.x * 256 + threadIdx.x;   // (b,h,q,d)
  const int d = idx & 63;
  const int q = (idx >> 6) & (S_LEN - 1);
  const int h = (idx >> 17) & (NH - 1);
  const int b = (idx >> 21) & 1;
  float m[NC], l[NC];
  float M = -1e30f;
#pragma unroll
  for (int c = 0; c < NC; ++c) {
    const size_t base = ((size_t)(c * 2 + b) * NH + h) * S_LEN + q;
    m[c] = mlp[base * 2];
    l[c] = mlp[base * 2 + 1];
    M = fmaxf(M, m[c]);
  }
  float lsum = 0.f, acc = 0.f;
#pragma unroll
  for (int c = 0; c < NC; ++c) {
    const size_t base = ((size_t)(c * 2 + b) * NH + h) * S_LEN + q;
    const float wgt = __expf(m[c] - M);
    lsum += wgt * l[c];
    acc += wgt * ctxp[base * DH + d];
  }
  ctx[((size_t)(b * S_LEN + q)) * DM + h * DH + d] = f2bf(acc / lsum);
}

extern "C" void kernel_launch(void* const* d_in, const int* in_sizes, int n_in,
                              void* d_out, int out_size, void* d_ws, size_t ws_size,
                              hipStream_t stream) {
  const float* q   = (const float*)d_in[0];
  const float* k   = (const float*)d_in[1];
  const float* v   = (const float*)d_in[2];
  const int*   msk = (const int*)d_in[3];
  const float* pb  = (const float*)d_in[4];
  const float* w_q = (const float*)d_in[5];
  const float* b_q = (const float*)d_in[6];
  const float* w_k = (const float*)d_in[7];
  const float* b_k = (const float*)d_in[8];
  const float* w_v = (const float*)d_in[9];
  const float* b_v = (const float*)d_in[10];
  const float* w_o = (const float*)d_in[11];
  const float* b_o = (const float*)d_in[12];
  float* out = (float*)d_out;

  char* ws = (char*)d_ws;
  u16* wq_bf = (u16*)(ws + ((size_t)0 << 20));
  u16* wk_bf = (u16*)(ws + ((size_t)2 << 20));
  u16* wv_bf = (u16*)(ws + ((size_t)4 << 20));
  u16* wo_bf = (u16*)(ws + ((size_t)6 << 20));
  u16* x_bf  = (u16*)(ws + ((size_t)8 << 20));   // 8MB staging; reused as ctx
  u16* Qb    = (u16*)(ws + ((size_t)16 << 20));
  u16* Kb    = (u16*)(ws + ((size_t)24 << 20));
  u16* Vtb   = (u16*)(ws + ((size_t)32 << 20));
  u64* mpk   = (u64*)(ws + ((size_t)40 << 20));  // 1 MB packed mask
  float* ctxp = (float*)(ws + ((size_t)48 << 20));  // 64 MB partial ctx
  float* mlp  = (float*)(ws + ((size_t)112 << 20)); // 2 MB partial m/l

  dim3 blk(256);
  const int n4w = DM * DM / 4;
  const int n4x = MTOK * DM / 4;
  k_convert<<<dim3(1024), blk, 0, stream>>>(w_q, wq_bf, n4w);
  k_convert<<<dim3(1024), blk, 0, stream>>>(w_k, wk_bf, n4w);
  k_convert<<<dim3(1024), blk, 0, stream>>>(w_v, wv_bf, n4w);
  k_convert<<<dim3(1024), blk, 0, stream>>>(w_o, wo_bf, n4w);
  k_maskpack<<<dim3(2048), blk, 0, stream>>>(msk, mpk, 2 * S_LEN * S_LEN);

  dim3 gg(32, 8);
  k_convert<<<dim3(2048), blk, 0, stream>>>(q, x_bf, n4x);
  k_gemm<0><<<gg, blk, 0, stream>>>(x_bf, wq_bf, b_q, Qb);
  k_convert<<<dim3(2048), blk, 0, stream>>>(k, x_bf, n4x);
  k_gemm<0><<<gg, blk, 0, stream>>>(x_bf, wk_bf, b_k, Kb);
  k_convert<<<dim3(2048), blk, 0, stream>>>(v, x_bf, n4x);
  k_gemm<1><<<gg, blk, 0, stream>>>(x_bf, wv_bf, b_v, Vtb);

  k_attn<<<dim3(32, NH, NC), blk, 0, stream>>>(Qb, Kb, Vtb, pb, mpk, ctxp, mlp);
  k_combine<<<dim3(2 * NH * S_LEN * DH / 256), blk, 0, stream>>>(ctxp, mlp, x_bf);
  k_gemm<2><<<gg, blk, 0, stream>>>(x_bf, wo_bf, b_o, out);
}

// Round 5
// 528.093 us; speedup vs baseline: 1.0014x; 1.0014x over previous
//
#include <hip/hip_runtime.h>
#include <hip/hip_bf16.h>

#define S_LEN 2048
#define DM 1024
#define NH 16
#define DH 64
#define MTOK 4096

typedef __attribute__((ext_vector_type(8))) __bf16 bf16x8;
typedef __attribute__((ext_vector_type(4))) float f32x4;
typedef unsigned short u16;
typedef unsigned long long u64;

__device__ __forceinline__ u16 f2bf(float f) {
  union { float f; unsigned u; } a; a.f = f;
  unsigned u = a.u;
  u += 0x7fffu + ((u >> 16) & 1u);   // RNE
  return (u16)(u >> 16);
}

__device__ __forceinline__ bf16x8 ld_bf8(const u16* p) {
  return *reinterpret_cast<const bf16x8*>(p);
}

// ---------------- fp32 -> bf16 convert ----------------
__global__ void k_convert(const float* __restrict__ src, u16* __restrict__ dst, int n4) {
  int i = blockIdx.x * blockDim.x + threadIdx.x;
  int stride = gridDim.x * blockDim.x;
  for (; i < n4; i += stride) {
    float4 v = reinterpret_cast<const float4*>(src)[i];
    ushort4 o;
    o.x = f2bf(v.x); o.y = f2bf(v.y); o.z = f2bf(v.z); o.w = f2bf(v.w);
    reinterpret_cast<ushort4*>(dst)[i] = o;
  }
}

// ---------------- mask bit-pack: [B][S][S] i32 -> [B][S][S/64] u64 ----------------
__global__ void k_maskpack(const int* __restrict__ m, u64* __restrict__ o, int n) {
  int i = blockIdx.x * blockDim.x + threadIdx.x;
  int stride = gridDim.x * blockDim.x;
  for (; i < n; i += stride) {
    u64 bal = __ballot(m[i] != 0);   // bit l = lane l's col (i aligned to 64 per wave)
    if ((i & 63) == 0) o[i >> 6] = bal;
  }
}

// ---------------- bf16 GEMM, B^T weights: C = A @ W^T + bias ----------------
// A [M=4096][K=1024] bf16 row-major, Bw [N=1024][K=1024] bf16 row-major.
// MODE 0: bf16 out scattered to [B*H][S][DH]   (Q, K buffers)
// MODE 1: bf16 out scattered to [B*H][DH][S]   (V transposed)
// MODE 2: f32 out row-major [M][N]             (final output)
template<int MODE>
__global__ __launch_bounds__(256) void k_gemm(
    const u16* __restrict__ A, const u16* __restrict__ Bw,
    const float* __restrict__ bias, void* __restrict__ dst) {
  constexpr int K = DM;
  __shared__ u16 As[128 * 32];
  __shared__ u16 Bs[128 * 32];
  const int tid = threadIdx.x;
  const int lane = tid & 63;
  const int wid = tid >> 6;
  const int wm = wid >> 1, wn = wid & 1;
  const int bm = blockIdx.x * 128;
  const int bn = blockIdx.y * 128;
  const int r0 = tid >> 2;           // 0..63
  const int c0 = (tid & 3) * 8;      // bf16 offset within 32-wide row
  const int fr = lane & 15;
  const int fk = (lane >> 4) * 8;

  f32x4 acc[4][4] = {};

  const u16* ga = A + (size_t)(bm + r0) * K + c0;
  const u16* gb = Bw + (size_t)(bn + r0) * K + c0;

  for (int kt = 0; kt < K; kt += 32) {
    __syncthreads();
    __builtin_amdgcn_global_load_lds(
        (const __attribute__((address_space(1))) void*)(ga + kt),
        (__attribute__((address_space(3))) void*)(&As[r0 * 32 + c0]), 16, 0, 0);
    __builtin_amdgcn_global_load_lds(
        (const __attribute__((address_space(1))) void*)(ga + (size_t)64 * K + kt),
        (__attribute__((address_space(3))) void*)(&As[(r0 + 64) * 32 + c0]), 16, 0, 0);
    __builtin_amdgcn_global_load_lds(
        (const __attribute__((address_space(1))) void*)(gb + kt),
        (__attribute__((address_space(3))) void*)(&Bs[r0 * 32 + c0]), 16, 0, 0);
    __builtin_amdgcn_global_load_lds(
        (const __attribute__((address_space(1))) void*)(gb + (size_t)64 * K + kt),
        (__attribute__((address_space(3))) void*)(&Bs[(r0 + 64) * 32 + c0]), 16, 0, 0);
    __syncthreads();
    bf16x8 af[4], bfr[4];
#pragma unroll
    for (int m = 0; m < 4; ++m) af[m] = ld_bf8(&As[(wm * 64 + m * 16 + fr) * 32 + fk]);
#pragma unroll
    for (int n = 0; n < 4; ++n) bfr[n] = ld_bf8(&Bs[(wn * 64 + n * 16 + fr) * 32 + fk]);
#pragma unroll
    for (int m = 0; m < 4; ++m)
#pragma unroll
      for (int n = 0; n < 4; ++n)
        acc[m][n] = __builtin_amdgcn_mfma_f32_16x16x32_bf16(af[m], bfr[n], acc[m][n], 0, 0, 0);
  }

  // C/D layout: col = lane&15, row = (lane>>4)*4 + reg
  const int cr = (lane >> 4) * 4;
  const int cc = lane & 15;
#pragma unroll
  for (int m = 0; m < 4; ++m) {
#pragma unroll
    for (int n = 0; n < 4; ++n) {
      const int colg = bn + wn * 64 + n * 16 + cc;
      const float bv = bias[colg];
      const int rbase = bm + wm * 64 + m * 16 + cr;
      if (MODE == 2) {
        float* o = (float*)dst;
#pragma unroll
        for (int r = 0; r < 4; ++r)
          o[(size_t)(rbase + r) * DM + colg] = acc[m][n][r] + bv;
      } else if (MODE == 0) {
        u16* o = (u16*)dst;
        const int h = colg >> 6, d = colg & 63;
#pragma unroll
        for (int r = 0; r < 4; ++r) {
          const int tok = rbase + r;
          const int b = tok >> 11, s = tok & 2047;
          o[(((size_t)(b * NH + h) * S_LEN) + s) * DH + d] = f2bf(acc[m][n][r] + bv);
        }
      } else {
        u16* o = (u16*)dst;
        const int h = colg >> 6, d = colg & 63;
        const int tok = rbase;
        const int b = tok >> 11, s = tok & 2047;
        ushort4 pk;
        pk.x = f2bf(acc[m][n][0] + bv);
        pk.y = f2bf(acc[m][n][1] + bv);
        pk.z = f2bf(acc[m][n][2] + bv);
        pk.w = f2bf(acc[m][n][3] + bv);
        *reinterpret_cast<ushort4*>(&o[(((size_t)(b * NH + h) * DH) + d) * S_LEN + s]) = pk;
      }
    }
  }
}

// ---------------- fused flash attention, LDS-free inner loop ----------------
// Swapped QK^T: S^T = mfma(A=K, B=Q) -> lane holds scores for q=lane&15,
// k = (lane>>4)*4 + r (+16*nb). Softmax = in-lane reg tree + 2 shfl_xor.
// PV via zero-padded 16x16x32: P already IS the A-fragment (no relayout),
// V^T 4-element loads fill the low half of B. No __shared__ anywhere.
// Qb,Kb: [B*H][S][64] bf16; Vt: [B*H][64][S] bf16; bias [H][S][S] f32;
// mpk [B][S][32] u64; ctx out: [B*S][1024] bf16
__global__ __launch_bounds__(256) void k_attn(
    const u16* __restrict__ Qb, const u16* __restrict__ Kb, const u16* __restrict__ Vt,
    const float* __restrict__ bias, const u64* __restrict__ mpk,
    u16* __restrict__ ctx) {
  const int tid = threadIdx.x;
  const int lane = tid & 63;
  const int w = tid >> 6;
  const int qt = blockIdx.x;
  const int h = blockIdx.y;
  const int lq = lane & 15;        // q-col during scores; d-col during PV
  const int lg = lane >> 4;        // 16-lane group
  const int q0 = qt * 64 + w * 16;

  const float* bp = bias + (size_t)h * S_LEN * S_LEN;

  // Q as B-fragment (col=q=lane&15, k-dim d=(lane>>4)*8+j), two halves of d=64
  bf16x8 qf[2][2];
  f32x4 cacc[2][4] = {};
  float m_run[2] = {-1e30f, -1e30f}, l_run[2] = {0.f, 0.f};
#pragma unroll
  for (int b = 0; b < 2; ++b) {
    const u16* Qp = Qb + (size_t)(b * NH + h) * S_LEN * DH;
    qf[b][0] = ld_bf8(&Qp[(size_t)(q0 + lq) * DH + lg * 8]);
    qf[b][1] = ld_bf8(&Qp[(size_t)(q0 + lq) * DH + 32 + lg * 8]);
  }

  for (int kt = 0; kt < S_LEN; kt += 64) {
    // bias: q per-lane row, k contiguous in regs -> float4 loads, shared across b
    float4 bv4[4];
#pragma unroll
    for (int nb = 0; nb < 4; ++nb)
      bv4[nb] = *reinterpret_cast<const float4*>(
          &bp[(size_t)(q0 + lq) * S_LEN + kt + nb * 16 + lg * 4]);

#pragma unroll
    for (int b = 0; b < 2; ++b) {
      const u16* Kp = Kb + (size_t)(b * NH + h) * S_LEN * DH;
      const u16* Vp = Vt + (size_t)(b * NH + h) * DH * S_LEN;
      const u64 mw = mpk[((size_t)b * S_LEN + q0 + lq) * 32 + (kt >> 6)];

      // ---- S^T = K Q^T : A=K rows(k), B=Q cols(q) ----
      f32x4 sc[4];
#pragma unroll
      for (int nb = 0; nb < 4; ++nb) {
        bf16x8 kf0 = ld_bf8(&Kp[(size_t)(kt + nb * 16 + lq) * DH + lg * 8]);
        bf16x8 kf1 = ld_bf8(&Kp[(size_t)(kt + nb * 16 + lq) * DH + 32 + lg * 8]);
        f32x4 z = {};
        z = __builtin_amdgcn_mfma_f32_16x16x32_bf16(kf0, qf[b][0], z, 0, 0, 0);
        sc[nb] = __builtin_amdgcn_mfma_f32_16x16x32_bf16(kf1, qf[b][1], z, 0, 0, 0);
      }
      // ---- scale + bias + mask (k index = nb*16 + lg*4 + r) ----
#pragma unroll
      for (int nb = 0; nb < 4; ++nb)
#pragma unroll
        for (int r = 0; r < 4; ++r) {
          const int shift = nb * 16 + lg * 4 + r;
          const float val = sc[nb][r] * 0.125f + ((const float*)&bv4[nb])[r];
          sc[nb][r] = ((mw >> shift) & 1) ? val : -1e9f;
        }
      // ---- max over k: in-lane tree (16 regs) + xor16 + xor32 ----
      float v0 = fmaxf(fmaxf(sc[0][0], sc[0][1]), fmaxf(sc[0][2], sc[0][3]));
      float v1 = fmaxf(fmaxf(sc[1][0], sc[1][1]), fmaxf(sc[1][2], sc[1][3]));
      float v2 = fmaxf(fmaxf(sc[2][0], sc[2][1]), fmaxf(sc[2][2], sc[2][3]));
      float v3 = fmaxf(fmaxf(sc[3][0], sc[3][1]), fmaxf(sc[3][2], sc[3][3]));
      float vm = fmaxf(fmaxf(v0, v1), fmaxf(v2, v3));
      vm = fmaxf(vm, __shfl_xor(vm, 16));
      vm = fmaxf(vm, __shfl_xor(vm, 32));
      // ---- online rescale; exact skip when running max unchanged ----
      if (!__all(vm <= m_run[b])) {
        const float mn = fmaxf(m_run[b], vm);
        const float corr = __expf(m_run[b] - mn);
        m_run[b] = mn;
        l_run[b] *= corr;
        float cr_[4];
#pragma unroll
        for (int r = 0; r < 4; ++r) cr_[r] = __shfl(corr, lg * 4 + r);
#pragma unroll
        for (int nd = 0; nd < 4; ++nd)
#pragma unroll
          for (int r = 0; r < 4; ++r) cacc[b][nd][r] *= cr_[r];
      }
      // ---- exp + sum ----
      float s0 = 0.f;
#pragma unroll
      for (int nb = 0; nb < 4; ++nb)
#pragma unroll
        for (int r = 0; r < 4; ++r) {
          const float p = __expf(sc[nb][r] - m_run[b]);
          sc[nb][r] = p;
          s0 += p;
        }
      s0 += __shfl_xor(s0, 16);
      s0 += __shfl_xor(s0, 32);
      l_run[b] += s0;
      // ---- pack P into zero-padded A-frags (no cross-lane!) ----
      bf16x8 pa[4];
#pragma unroll
      for (int nb = 0; nb < 4; ++nb) {
        union { unsigned u[4]; bf16x8 v; } pu;
        pu.u[0] = (unsigned)f2bf(sc[nb][0]) | ((unsigned)f2bf(sc[nb][1]) << 16);
        pu.u[1] = (unsigned)f2bf(sc[nb][2]) | ((unsigned)f2bf(sc[nb][3]) << 16);
        pu.u[2] = 0; pu.u[3] = 0;
        pa[nb] = pu.v;
      }
      // ---- ctx[q][d] += P V : A=P (rows q), B=V^T 4-elem loads (cols d) ----
#pragma unroll
      for (int nd = 0; nd < 4; ++nd) {
#pragma unroll
        for (int nb = 0; nb < 4; ++nb) {
          union { unsigned u[4]; bf16x8 v; } vu;
          const unsigned* vp = reinterpret_cast<const unsigned*>(
              &Vp[(size_t)(nd * 16 + lq) * S_LEN + kt + nb * 16 + lg * 4]);
          vu.u[0] = vp[0]; vu.u[1] = vp[1]; vu.u[2] = 0; vu.u[3] = 0;
          cacc[b][nd] = __builtin_amdgcn_mfma_f32_16x16x32_bf16(pa[nb], vu.v, cacc[b][nd], 0, 0, 0);
        }
      }
    }
  }
  // ---- epilogue: cacc row = q = lg*4+r, col = d = nd*16+lq ----
#pragma unroll
  for (int b = 0; b < 2; ++b)
#pragma unroll
    for (int r = 0; r < 4; ++r) {
      const float linv = 1.0f / __shfl(l_run[b], lg * 4 + r);
      const int tok = b * S_LEN + q0 + lg * 4 + r;
      u16* cp = ctx + (size_t)tok * DM + h * DH;
#pragma unroll
      for (int nd = 0; nd < 4; ++nd)
        cp[nd * 16 + lq] = f2bf(cacc[b][nd][r] * linv);
    }
}

extern "C" void kernel_launch(void* const* d_in, const int* in_sizes, int n_in,
                              void* d_out, int out_size, void* d_ws, size_t ws_size,
                              hipStream_t stream) {
  const float* q   = (const float*)d_in[0];
  const float* k   = (const float*)d_in[1];
  const float* v   = (const float*)d_in[2];
  const int*   msk = (const int*)d_in[3];
  const float* pb  = (const float*)d_in[4];
  const float* w_q = (const float*)d_in[5];
  const float* b_q = (const float*)d_in[6];
  const float* w_k = (const float*)d_in[7];
  const float* b_k = (const float*)d_in[8];
  const float* w_v = (const float*)d_in[9];
  const float* b_v = (const float*)d_in[10];
  const float* w_o = (const float*)d_in[11];
  const float* b_o = (const float*)d_in[12];
  float* out = (float*)d_out;

  char* ws = (char*)d_ws;
  u16* wq_bf = (u16*)(ws + ((size_t)0 << 20));
  u16* wk_bf = (u16*)(ws + ((size_t)2 << 20));
  u16* wv_bf = (u16*)(ws + ((size_t)4 << 20));
  u16* wo_bf = (u16*)(ws + ((size_t)6 << 20));
  u16* x_bf  = (u16*)(ws + ((size_t)8 << 20));   // 8MB staging; reused as ctx
  u16* Qb    = (u16*)(ws + ((size_t)16 << 20));
  u16* Kb    = (u16*)(ws + ((size_t)24 << 20));
  u16* Vtb   = (u16*)(ws + ((size_t)32 << 20));
  u64* mpk   = (u64*)(ws + ((size_t)40 << 20));  // 1 MB packed mask

  dim3 blk(256);
  const int n4w = DM * DM / 4;
  const int n4x = MTOK * DM / 4;
  k_convert<<<dim3(1024), blk, 0, stream>>>(w_q, wq_bf, n4w);
  k_convert<<<dim3(1024), blk, 0, stream>>>(w_k, wk_bf, n4w);
  k_convert<<<dim3(1024), blk, 0, stream>>>(w_v, wv_bf, n4w);
  k_convert<<<dim3(1024), blk, 0, stream>>>(w_o, wo_bf, n4w);
  k_maskpack<<<dim3(2048), blk, 0, stream>>>(msk, mpk, 2 * S_LEN * S_LEN);

  dim3 gg(32, 8);
  k_convert<<<dim3(2048), blk, 0, stream>>>(q, x_bf, n4x);
  k_gemm<0><<<gg, blk, 0, stream>>>(x_bf, wq_bf, b_q, Qb);
  k_convert<<<dim3(2048), blk, 0, stream>>>(k, x_bf, n4x);
  k_gemm<0><<<gg, blk, 0, stream>>>(x_bf, wk_bf, b_k, Kb);
  k_convert<<<dim3(2048), blk, 0, stream>>>(v, x_bf, n4x);
  k_gemm<1><<<gg, blk, 0, stream>>>(x_bf, wv_bf, b_v, Vtb);

  k_attn<<<dim3(32, NH), blk, 0, stream>>>(Qb, Kb, Vtb, pb, mpk, x_bf);
  k_gemm<2><<<gg, blk, 0, stream>>>(x_bf, wo_bf, b_o, out);
}

// Round 6
// 312.022 us; speedup vs baseline: 1.6949x; 1.6925x over previous
//
#include <hip/hip_runtime.h>
#include <hip/hip_bf16.h>

#define S_LEN 2048
#define DM 1024
#define NH 16
#define DH 64
#define MTOK 4096

typedef __attribute__((ext_vector_type(8))) __bf16 bf16x8;
typedef __attribute__((ext_vector_type(4))) float f32x4;
typedef __attribute__((ext_vector_type(16))) float f32x16;
typedef unsigned short u16;
typedef unsigned long long u64;

__device__ __forceinline__ u16 f2bf(float f) {
  union { float f; unsigned u; } a; a.f = f;
  unsigned u = a.u;
  u += 0x7fffu + ((u >> 16) & 1u);   // RNE
  return (u16)(u >> 16);
}

__device__ __forceinline__ bf16x8 ld_bf8(const u16* p) {
  return *reinterpret_cast<const bf16x8*>(p);
}

// ---------------- fp32 -> bf16 convert ----------------
__global__ void k_convert(const float* __restrict__ src, u16* __restrict__ dst, int n4) {
  int i = blockIdx.x * blockDim.x + threadIdx.x;
  int stride = gridDim.x * blockDim.x;
  for (; i < n4; i += stride) {
    float4 v = reinterpret_cast<const float4*>(src)[i];
    ushort4 o;
    o.x = f2bf(v.x); o.y = f2bf(v.y); o.z = f2bf(v.z); o.w = f2bf(v.w);
    reinterpret_cast<ushort4*>(dst)[i] = o;
  }
}

// ---------------- mask bit-pack: [B][S][S] i32 -> [B][S][S/64] u64 ----------------
__global__ void k_maskpack(const int* __restrict__ m, u64* __restrict__ o, int n) {
  int i = blockIdx.x * blockDim.x + threadIdx.x;
  int stride = gridDim.x * blockDim.x;
  for (; i < n; i += stride) {
    u64 bal = __ballot(m[i] != 0);
    if ((i & 63) == 0) o[i >> 6] = bal;
  }
}

// ---------------- bf16 GEMM, B^T weights: C = A @ W^T + bias ----------------
template<int MODE>
__global__ __launch_bounds__(256) void k_gemm(
    const u16* __restrict__ A, const u16* __restrict__ Bw,
    const float* __restrict__ bias, void* __restrict__ dst) {
  constexpr int K = DM;
  __shared__ u16 As[128 * 32];
  __shared__ u16 Bs[128 * 32];
  const int tid = threadIdx.x;
  const int lane = tid & 63;
  const int wid = tid >> 6;
  const int wm = wid >> 1, wn = wid & 1;
  const int bm = blockIdx.x * 128;
  const int bn = blockIdx.y * 128;
  const int r0 = tid >> 2;
  const int c0 = (tid & 3) * 8;
  const int fr = lane & 15;
  const int fk = (lane >> 4) * 8;

  f32x4 acc[4][4] = {};

  const u16* ga = A + (size_t)(bm + r0) * K + c0;
  const u16* gb = Bw + (size_t)(bn + r0) * K + c0;

  for (int kt = 0; kt < K; kt += 32) {
    __syncthreads();
    __builtin_amdgcn_global_load_lds(
        (const __attribute__((address_space(1))) void*)(ga + kt),
        (__attribute__((address_space(3))) void*)(&As[r0 * 32 + c0]), 16, 0, 0);
    __builtin_amdgcn_global_load_lds(
        (const __attribute__((address_space(1))) void*)(ga + (size_t)64 * K + kt),
        (__attribute__((address_space(3))) void*)(&As[(r0 + 64) * 32 + c0]), 16, 0, 0);
    __builtin_amdgcn_global_load_lds(
        (const __attribute__((address_space(1))) void*)(gb + kt),
        (__attribute__((address_space(3))) void*)(&Bs[r0 * 32 + c0]), 16, 0, 0);
    __builtin_amdgcn_global_load_lds(
        (const __attribute__((address_space(1))) void*)(gb + (size_t)64 * K + kt),
        (__attribute__((address_space(3))) void*)(&Bs[(r0 + 64) * 32 + c0]), 16, 0, 0);
    __syncthreads();
    bf16x8 af[4], bfr[4];
#pragma unroll
    for (int m = 0; m < 4; ++m) af[m] = ld_bf8(&As[(wm * 64 + m * 16 + fr) * 32 + fk]);
#pragma unroll
    for (int n = 0; n < 4; ++n) bfr[n] = ld_bf8(&Bs[(wn * 64 + n * 16 + fr) * 32 + fk]);
#pragma unroll
    for (int m = 0; m < 4; ++m)
#pragma unroll
      for (int n = 0; n < 4; ++n)
        acc[m][n] = __builtin_amdgcn_mfma_f32_16x16x32_bf16(af[m], bfr[n], acc[m][n], 0, 0, 0);
  }

  const int cr = (lane >> 4) * 4;
  const int cc = lane & 15;
#pragma unroll
  for (int m = 0; m < 4; ++m) {
#pragma unroll
    for (int n = 0; n < 4; ++n) {
      const int colg = bn + wn * 64 + n * 16 + cc;
      const float bv = bias[colg];
      const int rbase = bm + wm * 64 + m * 16 + cr;
      if (MODE == 2) {
        float* o = (float*)dst;
#pragma unroll
        for (int r = 0; r < 4; ++r)
          o[(size_t)(rbase + r) * DM + colg] = acc[m][n][r] + bv;
      } else if (MODE == 0) {
        u16* o = (u16*)dst;
        const int h = colg >> 6, d = colg & 63;
#pragma unroll
        for (int r = 0; r < 4; ++r) {
          const int tok = rbase + r;
          const int b = tok >> 11, s = tok & 2047;
          o[(((size_t)(b * NH + h) * S_LEN) + s) * DH + d] = f2bf(acc[m][n][r] + bv);
        }
      } else {
        u16* o = (u16*)dst;
        const int h = colg >> 6, d = colg & 63;
        const int tok = rbase;
        const int b = tok >> 11, s = tok & 2047;
        ushort4 pk;
        pk.x = f2bf(acc[m][n][0] + bv);
        pk.y = f2bf(acc[m][n][1] + bv);
        pk.z = f2bf(acc[m][n][2] + bv);
        pk.w = f2bf(acc[m][n][3] + bv);
        *reinterpret_cast<ushort4*>(&o[(((size_t)(b * NH + h) * DH) + d) * S_LEN + s]) = pk;
      }
    }
  }
}

// ---------------- fused flash attention, m214-style 32x32 MFMA + LDS-staged K/V ----
// 4 waves x 32 q-rows; KVBLK=64; both batches fused per block (bias read once).
// K,V tiles (both b) double-buffered in LDS via global_load_lds with pre-swizzled
// source (XOR swizzle ((row&7)<<3) elems), read back as 32x32x16 MFMA A-frags.
// Swapped QK^T: S^T = mfma(A=K, B=Q) -> lane holds q=lane&31 col; softmax in-lane
// (32 regs) + one shfl_xor(32). P repacked to B-frags via pack + shfl_xor(32).
// PV: ctx^T = mfma(A=V^T, B=P^T). No cross-lane softmax chains, no P LDS trip.
__global__ __launch_bounds__(256) void k_attn(
    const u16* __restrict__ Qb, const u16* __restrict__ Kb, const u16* __restrict__ Vt,
    const float* __restrict__ bias, const u64* __restrict__ mpk,
    u16* __restrict__ ctx) {
  __shared__ u16 lds[2][4][4096];   // [buf][K b0, K b1, V b0, V b1][64*64]
  const int tid = threadIdx.x;
  const int lane = tid & 63;
  const int w = tid >> 6;
  const int h = blockIdx.y;
  const int q0 = blockIdx.x * 128 + w * 32;
  const int lq = lane & 31;
  const int hi = lane >> 5;

  const float* bp = bias + (size_t)h * S_LEN * S_LEN;

  // Q as B-fragment: col=q=lane&31, k-elem d = d0*16 + hi*8 + j
  bf16x8 qf[2][4];
  f32x16 cacc[2][2] = {};
  float m_run[2] = {-1e30f, -1e30f}, l_run[2] = {0.f, 0.f};
#pragma unroll
  for (int b = 0; b < 2; ++b) {
    const u16* Qp = Qb + (size_t)(b * NH + h) * S_LEN * DH;
#pragma unroll
    for (int d0 = 0; d0 < 4; ++d0)
      qf[b][d0] = ld_bf8(&Qp[(size_t)(q0 + lq) * DH + d0 * 16 + hi * 8]);
  }

  // staging: thread covers LDS elems [(i*256+tid)*8, +8); row rr = elems/64;
  // source column pre-swizzled so linear LDS dest holds swizzled layout.
#define STAGE(ktv, cb) {                                                          \
    _Pragma("unroll") for (int i = 0; i < 2; ++i) {                               \
      const int el = (i * 256 + tid) * 8;                                         \
      const int rr = el >> 6;                                                     \
      const int ce = ((tid & 7) * 8) ^ ((rr & 7) << 3);                           \
      _Pragma("unroll") for (int b2 = 0; b2 < 2; ++b2) {                          \
        const u16* ksrc = Kb + (size_t)(b2 * NH + h) * S_LEN * DH                 \
                          + (size_t)((ktv) + rr) * DH + ce;                       \
        const u16* vsrc = Vt + (size_t)(b2 * NH + h) * DH * S_LEN                 \
                          + (size_t)rr * S_LEN + (ktv) + ce;                      \
        __builtin_amdgcn_global_load_lds(                                         \
            (const __attribute__((address_space(1))) void*)ksrc,                  \
            (__attribute__((address_space(3))) void*)&lds[cb][b2][el], 16, 0, 0); \
        __builtin_amdgcn_global_load_lds(                                         \
            (const __attribute__((address_space(1))) void*)vsrc,                  \
            (__attribute__((address_space(3))) void*)&lds[cb][2 + b2][el], 16, 0, 0); \
      } } }

#define LDSREAD(cb, tile, row, cel) \
    ld_bf8(&lds[cb][tile][(row) * 64 + (((cel)) ^ (((row) & 7) << 3))])

  STAGE(0, 0);
  int c = 0;
  for (int t = 0; t < S_LEN / 64; ++t) {
    const int ktv = t * 64;
    __syncthreads();   // implicit vmcnt(0): buf c staged; prev iter reads done
    if (t + 1 < S_LEN / 64) STAGE(ktv + 64, c ^ 1);

    // bias (float4, shared across b) + packed mask, issued early
    float4 bv[2][4];
#pragma unroll
    for (int kb = 0; kb < 2; ++kb)
#pragma unroll
      for (int rq = 0; rq < 4; ++rq)
        bv[kb][rq] = *reinterpret_cast<const float4*>(
            &bp[(size_t)(q0 + lq) * S_LEN + ktv + kb * 32 + rq * 8 + hi * 4]);
    u64 mwb[2];
    mwb[0] = mpk[((size_t)(q0 + lq)) * 32 + (ktv >> 6)];
    mwb[1] = mpk[((size_t)(S_LEN + q0 + lq)) * 32 + (ktv >> 6)];

#pragma unroll
    for (int b = 0; b < 2; ++b) {
      // ---- S^T = K Q^T over d=64 (4 MFMAs per 32-k block) ----
      f32x16 sc0 = {}, sc1 = {};
#pragma unroll
      for (int d0 = 0; d0 < 4; ++d0) {
        bf16x8 ka0 = LDSREAD(c, b, 0 * 32 + lq, d0 * 16 + hi * 8);
        sc0 = __builtin_amdgcn_mfma_f32_32x32x16_bf16(ka0, qf[b][d0], sc0, 0, 0, 0);
        bf16x8 ka1 = LDSREAD(c, b, 1 * 32 + lq, d0 * 16 + hi * 8);
        sc1 = __builtin_amdgcn_mfma_f32_32x32x16_bf16(ka1, qf[b][d0], sc1, 0, 0, 0);
      }
      // ---- scale + bias + mask; k_rel = kb*32 + (r&3)+8*(r>>2)+4*hi ----
#pragma unroll
      for (int r = 0; r < 16; ++r) {
        const int cr_ = (r & 3) + 8 * (r >> 2);
        const float v0_ = sc0[r] * 0.125f + ((const float*)&bv[0][r >> 2])[r & 3];
        sc0[r] = ((mwb[b] >> (cr_ + 4 * hi)) & 1) ? v0_ : -1e9f;
        const float v1_ = sc1[r] * 0.125f + ((const float*)&bv[1][r >> 2])[r & 3];
        sc1[r] = ((mwb[b] >> (32 + cr_ + 4 * hi)) & 1) ? v1_ : -1e9f;
      }
      // ---- row max: in-lane tree + one cross-half exchange ----
      float vm = fmaxf(sc0[0], sc1[0]);
#pragma unroll
      for (int r = 1; r < 16; ++r) vm = fmaxf(vm, fmaxf(sc0[r], sc1[r]));
      vm = fmaxf(vm, __shfl_xor(vm, 32));
      if (!__all(vm <= m_run[b])) {
        const float mn = fmaxf(m_run[b], vm);
        const float corr = __expf(m_run[b] - mn);
        m_run[b] = mn;
        l_run[b] *= corr;
#pragma unroll
        for (int r = 0; r < 16; ++r) { cacc[b][0][r] *= corr; cacc[b][1][r] *= corr; }
      }
      // ---- exp + sum ----
      float ssum = 0.f;
#pragma unroll
      for (int r = 0; r < 16; ++r) {
        const float p0 = __expf(sc0[r] - m_run[b]); sc0[r] = p0;
        const float p1 = __expf(sc1[r] - m_run[b]); sc1[r] = p1;
        ssum += p0 + p1;
      }
      ssum += __shfl_xor(ssum, 32);
      l_run[b] += ssum;
      // ---- pack P (bf16 pairs) then cross-half exchange into B-frags ----
      unsigned pw0[8], pw1[8];
#pragma unroll
      for (int i2 = 0; i2 < 8; ++i2) {
        pw0[i2] = (unsigned)f2bf(sc0[2 * i2]) | ((unsigned)f2bf(sc0[2 * i2 + 1]) << 16);
        pw1[i2] = (unsigned)f2bf(sc1[2 * i2]) | ((unsigned)f2bf(sc1[2 * i2 + 1]) << 16);
      }
      bf16x8 pf[4];
#pragma unroll
      for (int kb = 0; kb < 2; ++kb)
#pragma unroll
        for (int ch = 0; ch < 2; ++ch) {
          const unsigned a0 = kb ? pw1[ch * 4 + 0] : pw0[ch * 4 + 0];
          const unsigned a1 = kb ? pw1[ch * 4 + 1] : pw0[ch * 4 + 1];
          const unsigned a2 = kb ? pw1[ch * 4 + 2] : pw0[ch * 4 + 2];
          const unsigned a3 = kb ? pw1[ch * 4 + 3] : pw0[ch * 4 + 3];
          const unsigned sx0 = __shfl_xor(a0, 32), sx1 = __shfl_xor(a1, 32);
          const unsigned sx2 = __shfl_xor(a2, 32), sx3 = __shfl_xor(a3, 32);
          union { unsigned u[4]; bf16x8 v; } f;
          f.u[0] = hi ? sx2 : a0;
          f.u[1] = hi ? sx3 : a1;
          f.u[2] = hi ? a2 : sx0;
          f.u[3] = hi ? a3 : sx1;
          pf[kb * 2 + ch] = f.v;
        }
      // ---- ctx^T += V^T P^T (A=V^T rows d, B=P cols q) ----
#pragma unroll
      for (int db = 0; db < 2; ++db)
#pragma unroll
        for (int kc = 0; kc < 4; ++kc) {
          bf16x8 va = LDSREAD(c, 2 + b, db * 32 + lq, kc * 16 + hi * 8);
          cacc[b][db] = __builtin_amdgcn_mfma_f32_32x32x16_bf16(va, pf[kc], cacc[b][db], 0, 0, 0);
        }
    }
    c ^= 1;
  }
#undef STAGE
#undef LDSREAD
  // ---- epilogue: ctx^T reg (d=db*32+crow(r,hi), q=lane&31) -> ctx[tok][h*64+d] ----
#pragma unroll
  for (int b = 0; b < 2; ++b) {
    const float linv = 1.0f / l_run[b];
    u16* cp = ctx + ((size_t)(b * S_LEN + q0 + lq)) * DM + h * DH;
#pragma unroll
    for (int db = 0; db < 2; ++db)
#pragma unroll
      for (int r = 0; r < 16; ++r)
        cp[db * 32 + (r & 3) + 8 * (r >> 2) + 4 * hi] = f2bf(cacc[b][db][r] * linv);
  }
}

extern "C" void kernel_launch(void* const* d_in, const int* in_sizes, int n_in,
                              void* d_out, int out_size, void* d_ws, size_t ws_size,
                              hipStream_t stream) {
  const float* q   = (const float*)d_in[0];
  const float* k   = (const float*)d_in[1];
  const float* v   = (const float*)d_in[2];
  const int*   msk = (const int*)d_in[3];
  const float* pb  = (const float*)d_in[4];
  const float* w_q = (const float*)d_in[5];
  const float* b_q = (const float*)d_in[6];
  const float* w_k = (const float*)d_in[7];
  const float* b_k = (const float*)d_in[8];
  const float* w_v = (const float*)d_in[9];
  const float* b_v = (const float*)d_in[10];
  const float* w_o = (const float*)d_in[11];
  const float* b_o = (const float*)d_in[12];
  float* out = (float*)d_out;

  char* ws = (char*)d_ws;
  u16* wq_bf = (u16*)(ws + ((size_t)0 << 20));
  u16* wk_bf = (u16*)(ws + ((size_t)2 << 20));
  u16* wv_bf = (u16*)(ws + ((size_t)4 << 20));
  u16* wo_bf = (u16*)(ws + ((size_t)6 << 20));
  u16* x_bf  = (u16*)(ws + ((size_t)8 << 20));   // staging; reused as ctx
  u16* Qb    = (u16*)(ws + ((size_t)16 << 20));
  u16* Kb    = (u16*)(ws + ((size_t)24 << 20));
  u16* Vtb   = (u16*)(ws + ((size_t)32 << 20));
  u64* mpk   = (u64*)(ws + ((size_t)40 << 20));  // 1 MB packed mask

  dim3 blk(256);
  const int n4w = DM * DM / 4;
  const int n4x = MTOK * DM / 4;
  k_convert<<<dim3(1024), blk, 0, stream>>>(w_q, wq_bf, n4w);
  k_convert<<<dim3(1024), blk, 0, stream>>>(w_k, wk_bf, n4w);
  k_convert<<<dim3(1024), blk, 0, stream>>>(w_v, wv_bf, n4w);
  k_convert<<<dim3(1024), blk, 0, stream>>>(w_o, wo_bf, n4w);
  k_maskpack<<<dim3(2048), blk, 0, stream>>>(msk, mpk, 2 * S_LEN * S_LEN);

  dim3 gg(32, 8);
  k_convert<<<dim3(2048), blk, 0, stream>>>(q, x_bf, n4x);
  k_gemm<0><<<gg, blk, 0, stream>>>(x_bf, wq_bf, b_q, Qb);
  k_convert<<<dim3(2048), blk, 0, stream>>>(k, x_bf, n4x);
  k_gemm<0><<<gg, blk, 0, stream>>>(x_bf, wk_bf, b_k, Kb);
  k_convert<<<dim3(2048), blk, 0, stream>>>(v, x_bf, n4x);
  k_gemm<1><<<gg, blk, 0, stream>>>(x_bf, wv_bf, b_v, Vtb);

  k_attn<<<dim3(16, NH), blk, 0, stream>>>(Qb, Kb, Vtb, pb, mpk, x_bf);
  k_gemm<2><<<gg, blk, 0, stream>>>(x_bf, wo_bf, b_o, out);
}

// Round 7
// 287.434 us; speedup vs baseline: 1.8399x; 1.0855x over previous
//
#include <hip/hip_runtime.h>
#include <hip/hip_bf16.h>

#define S_LEN 2048
#define DM 1024
#define NH 16
#define DH 64
#define MTOK 4096

typedef __attribute__((ext_vector_type(8))) __bf16 bf16x8;
typedef __attribute__((ext_vector_type(4))) float f32x4;
typedef __attribute__((ext_vector_type(16))) float f32x16;
typedef unsigned short u16;
typedef unsigned long long u64;

__device__ __forceinline__ u16 f2bf(float f) {
  union { float f; unsigned u; } a; a.f = f;
  unsigned u = a.u;
  u += 0x7fffu + ((u >> 16) & 1u);   // RNE
  return (u16)(u >> 16);
}

__device__ __forceinline__ bf16x8 ld_bf8(const u16* p) {
  return *reinterpret_cast<const bf16x8*>(p);
}

// ---------------- fp32 -> bf16 convert ----------------
__global__ void k_convert(const float* __restrict__ src, u16* __restrict__ dst, int n4) {
  int i = blockIdx.x * blockDim.x + threadIdx.x;
  int stride = gridDim.x * blockDim.x;
  for (; i < n4; i += stride) {
    float4 v = reinterpret_cast<const float4*>(src)[i];
    ushort4 o;
    o.x = f2bf(v.x); o.y = f2bf(v.y); o.z = f2bf(v.z); o.w = f2bf(v.w);
    reinterpret_cast<ushort4*>(dst)[i] = o;
  }
}

// ---------------- mask bit-pack: [B][S][S] i32 -> [B][S][S/64] u64 ----------------
__global__ void k_maskpack(const int* __restrict__ m, u64* __restrict__ o, int n) {
  int i = blockIdx.x * blockDim.x + threadIdx.x;
  int stride = gridDim.x * blockDim.x;
  for (; i < n; i += stride) {
    u64 bal = __ballot(m[i] != 0);
    if ((i & 63) == 0) o[i >> 6] = bal;
  }
}

// ---------------- bf16 GEMM, B^T weights: C = A @ W^T + bias ----------------
template<int MODE>
__global__ __launch_bounds__(256) void k_gemm(
    const u16* __restrict__ A, const u16* __restrict__ Bw,
    const float* __restrict__ bias, void* __restrict__ dst) {
  constexpr int K = DM;
  __shared__ u16 As[128 * 32];
  __shared__ u16 Bs[128 * 32];
  const int tid = threadIdx.x;
  const int lane = tid & 63;
  const int wid = tid >> 6;
  const int wm = wid >> 1, wn = wid & 1;
  const int bm = blockIdx.x * 128;
  const int bn = blockIdx.y * 128;
  const int r0 = tid >> 2;
  const int c0 = (tid & 3) * 8;
  const int fr = lane & 15;
  const int fk = (lane >> 4) * 8;

  f32x4 acc[4][4] = {};

  const u16* ga = A + (size_t)(bm + r0) * K + c0;
  const u16* gb = Bw + (size_t)(bn + r0) * K + c0;

  for (int kt = 0; kt < K; kt += 32) {
    __syncthreads();
    __builtin_amdgcn_global_load_lds(
        (const __attribute__((address_space(1))) void*)(ga + kt),
        (__attribute__((address_space(3))) void*)(&As[r0 * 32 + c0]), 16, 0, 0);
    __builtin_amdgcn_global_load_lds(
        (const __attribute__((address_space(1))) void*)(ga + (size_t)64 * K + kt),
        (__attribute__((address_space(3))) void*)(&As[(r0 + 64) * 32 + c0]), 16, 0, 0);
    __builtin_amdgcn_global_load_lds(
        (const __attribute__((address_space(1))) void*)(gb + kt),
        (__attribute__((address_space(3))) void*)(&Bs[r0 * 32 + c0]), 16, 0, 0);
    __builtin_amdgcn_global_load_lds(
        (const __attribute__((address_space(1))) void*)(gb + (size_t)64 * K + kt),
        (__attribute__((address_space(3))) void*)(&Bs[(r0 + 64) * 32 + c0]), 16, 0, 0);
    __syncthreads();
    bf16x8 af[4], bfr[4];
#pragma unroll
    for (int m = 0; m < 4; ++m) af[m] = ld_bf8(&As[(wm * 64 + m * 16 + fr) * 32 + fk]);
#pragma unroll
    for (int n = 0; n < 4; ++n) bfr[n] = ld_bf8(&Bs[(wn * 64 + n * 16 + fr) * 32 + fk]);
#pragma unroll
    for (int m = 0; m < 4; ++m)
#pragma unroll
      for (int n = 0; n < 4; ++n)
        acc[m][n] = __builtin_amdgcn_mfma_f32_16x16x32_bf16(af[m], bfr[n], acc[m][n], 0, 0, 0);
  }

  const int cr = (lane >> 4) * 4;
  const int cc = lane & 15;
#pragma unroll
  for (int m = 0; m < 4; ++m) {
#pragma unroll
    for (int n = 0; n < 4; ++n) {
      const int colg = bn + wn * 64 + n * 16 + cc;
      const float bv = bias[colg];
      const int rbase = bm + wm * 64 + m * 16 + cr;
      if (MODE == 2) {
        float* o = (float*)dst;
#pragma unroll
        for (int r = 0; r < 4; ++r)
          o[(size_t)(rbase + r) * DM + colg] = acc[m][n][r] + bv;
      } else if (MODE == 0) {
        u16* o = (u16*)dst;
        const int h = colg >> 6, d = colg & 63;
#pragma unroll
        for (int r = 0; r < 4; ++r) {
          const int tok = rbase + r;
          const int b = tok >> 11, s = tok & 2047;
          o[(((size_t)(b * NH + h) * S_LEN) + s) * DH + d] = f2bf(acc[m][n][r] + bv);
        }
      } else {
        u16* o = (u16*)dst;
        const int h = colg >> 6, d = colg & 63;
        const int tok = rbase;
        const int b = tok >> 11, s = tok & 2047;
        ushort4 pk;
        pk.x = f2bf(acc[m][n][0] + bv);
        pk.y = f2bf(acc[m][n][1] + bv);
        pk.z = f2bf(acc[m][n][2] + bv);
        pk.w = f2bf(acc[m][n][3] + bv);
        *reinterpret_cast<ushort4*>(&o[(((size_t)(b * NH + h) * DH) + d) * S_LEN + s]) = pk;
      }
    }
  }
}

// ---------------- fused flash attention ----------------
// 4 waves = (qsub, batch) split: wave w -> b = w>>1, q0 = blk*64 + (w&1)*32.
// Grid (32,16) = 512 blocks = 2 blocks/CU = 2 waves/SIMD.
// K,V tiles (both b) double-buffered in LDS (global_load_lds, pre-swizzled src);
// swapped 32x32x16 QK^T, in-register softmax, P repack via shfl_xor(32),
// PV from LDS V^T. Bias prefetched one kt-iter ahead (bvA/bvB register stages).
__global__ __launch_bounds__(256, 2) void k_attn(
    const u16* __restrict__ Qb, const u16* __restrict__ Kb, const u16* __restrict__ Vt,
    const float* __restrict__ bias, const u64* __restrict__ mpk,
    u16* __restrict__ ctx) {
  __shared__ u16 lds[2][4][4096];   // [buf][K b0, K b1, V b0, V b1][64*64]
  const int tid = threadIdx.x;
  const int lane = tid & 63;
  const int w = tid >> 6;
  const int b = w >> 1;
  const int h = blockIdx.y;
  const int q0 = blockIdx.x * 64 + (w & 1) * 32;
  const int lq = lane & 31;
  const int hi = lane >> 5;

  const float* bp = bias + (size_t)h * S_LEN * S_LEN;

  // Q as B-fragment: col=q=lane&31, k-elem d = d0*16 + hi*8 + j
  bf16x8 qf[4];
  f32x16 cacc[2] = {};
  float m_run = -1e30f, l_run = 0.f;
  {
    const u16* Qp = Qb + (size_t)(b * NH + h) * S_LEN * DH;
#pragma unroll
    for (int d0 = 0; d0 < 4; ++d0)
      qf[d0] = ld_bf8(&Qp[(size_t)(q0 + lq) * DH + d0 * 16 + hi * 8]);
  }

#define STAGE(ktv, cb) {                                                          \
    _Pragma("unroll") for (int i = 0; i < 2; ++i) {                               \
      const int el = (i * 256 + tid) * 8;                                         \
      const int rr = el >> 6;                                                     \
      const int ce = ((tid & 7) * 8) ^ ((rr & 7) << 3);                           \
      _Pragma("unroll") for (int b2 = 0; b2 < 2; ++b2) {                          \
        const u16* ksrc = Kb + (size_t)(b2 * NH + h) * S_LEN * DH                 \
                          + (size_t)((ktv) + rr) * DH + ce;                       \
        const u16* vsrc = Vt + (size_t)(b2 * NH + h) * DH * S_LEN                 \
                          + (size_t)rr * S_LEN + (ktv) + ce;                      \
        __builtin_amdgcn_global_load_lds(                                         \
            (const __attribute__((address_space(1))) void*)ksrc,                  \
            (__attribute__((address_space(3))) void*)&lds[cb][b2][el], 16, 0, 0); \
        __builtin_amdgcn_global_load_lds(                                         \
            (const __attribute__((address_space(1))) void*)vsrc,                  \
            (__attribute__((address_space(3))) void*)&lds[cb][2 + b2][el], 16, 0, 0); \
      } } }

#define LDSREAD(cb, tile, row, cel) \
    ld_bf8(&lds[cb][tile][(row) * 64 + (((cel)) ^ (((row) & 7) << 3))])

#define LOADB(BV, ktv) {                                                          \
    _Pragma("unroll") for (int kb = 0; kb < 2; ++kb)                              \
      _Pragma("unroll") for (int rq = 0; rq < 4; ++rq)                            \
        BV[kb][rq] = *reinterpret_cast<const float4*>(                            \
            &bp[(size_t)(q0 + lq) * S_LEN + (ktv) + kb * 32 + rq * 8 + hi * 4]); }

#define BODY(T, BV, BVN) {                                                        \
    const int ktv = (T) * 64;                                                     \
    __syncthreads();                                                              \
    if ((T) + 1 < S_LEN / 64) { STAGE(ktv + 64, c ^ 1); LOADB(BVN, ktv + 64); }   \
    const u64 mw = mpk[((size_t)(b * S_LEN + q0 + lq)) * 32 + (ktv >> 6)];        \
    f32x16 sc0 = {}, sc1 = {};                                                    \
    _Pragma("unroll") for (int d0 = 0; d0 < 4; ++d0) {                            \
      bf16x8 ka0 = LDSREAD(c, b, lq, d0 * 16 + hi * 8);                           \
      sc0 = __builtin_amdgcn_mfma_f32_32x32x16_bf16(ka0, qf[d0], sc0, 0, 0, 0);   \
      bf16x8 ka1 = LDSREAD(c, b, 32 + lq, d0 * 16 + hi * 8);                      \
      sc1 = __builtin_amdgcn_mfma_f32_32x32x16_bf16(ka1, qf[d0], sc1, 0, 0, 0);   \
    }                                                                             \
    _Pragma("unroll") for (int r = 0; r < 16; ++r) {                              \
      const int cr_ = (r & 3) + 8 * (r >> 2);                                     \
      const float v0_ = sc0[r] * 0.125f + ((const float*)&BV[0][r >> 2])[r & 3];  \
      sc0[r] = ((mw >> (cr_ + 4 * hi)) & 1) ? v0_ : -1e9f;                        \
      const float v1_ = sc1[r] * 0.125f + ((const float*)&BV[1][r >> 2])[r & 3];  \
      sc1[r] = ((mw >> (32 + cr_ + 4 * hi)) & 1) ? v1_ : -1e9f;                   \
    }                                                                             \
    float vm = fmaxf(sc0[0], sc1[0]);                                             \
    _Pragma("unroll") for (int r = 1; r < 16; ++r)                                \
      vm = fmaxf(vm, fmaxf(sc0[r], sc1[r]));                                      \
    vm = fmaxf(vm, __shfl_xor(vm, 32));                                           \
    if (!__all(vm <= m_run)) {                                                    \
      const float mn = fmaxf(m_run, vm);                                          \
      const float corr = __expf(m_run - mn);                                      \
      m_run = mn;                                                                 \
      l_run *= corr;                                                              \
      _Pragma("unroll") for (int r = 0; r < 16; ++r) {                            \
        cacc[0][r] *= corr; cacc[1][r] *= corr; }                                 \
    }                                                                             \
    float ssum = 0.f;                                                             \
    _Pragma("unroll") for (int r = 0; r < 16; ++r) {                              \
      const float p0 = __expf(sc0[r] - m_run); sc0[r] = p0;                       \
      const float p1 = __expf(sc1[r] - m_run); sc1[r] = p1;                       \
      ssum += p0 + p1;                                                            \
    }                                                                             \
    ssum += __shfl_xor(ssum, 32);                                                 \
    l_run += ssum;                                                                \
    unsigned pw0[8], pw1[8];                                                      \
    _Pragma("unroll") for (int i2 = 0; i2 < 8; ++i2) {                            \
      pw0[i2] = (unsigned)f2bf(sc0[2 * i2]) | ((unsigned)f2bf(sc0[2 * i2 + 1]) << 16); \
      pw1[i2] = (unsigned)f2bf(sc1[2 * i2]) | ((unsigned)f2bf(sc1[2 * i2 + 1]) << 16); \
    }                                                                             \
    bf16x8 pf[4];                                                                 \
    _Pragma("unroll") for (int kb = 0; kb < 2; ++kb)                              \
      _Pragma("unroll") for (int ch = 0; ch < 2; ++ch) {                          \
        const unsigned a0 = kb ? pw1[ch * 4 + 0] : pw0[ch * 4 + 0];               \
        const unsigned a1 = kb ? pw1[ch * 4 + 1] : pw0[ch * 4 + 1];               \
        const unsigned a2 = kb ? pw1[ch * 4 + 2] : pw0[ch * 4 + 2];               \
        const unsigned a3 = kb ? pw1[ch * 4 + 3] : pw0[ch * 4 + 3];               \
        const unsigned sx0 = __shfl_xor(a0, 32), sx1 = __shfl_xor(a1, 32);        \
        const unsigned sx2 = __shfl_xor(a2, 32), sx3 = __shfl_xor(a3, 32);        \
        union { unsigned u[4]; bf16x8 v; } f;                                     \
        f.u[0] = hi ? sx2 : a0;                                                   \
        f.u[1] = hi ? sx3 : a1;                                                   \
        f.u[2] = hi ? a2 : sx0;                                                   \
        f.u[3] = hi ? a3 : sx1;                                                   \
        pf[kb * 2 + ch] = f.v;                                                    \
      }                                                                           \
    _Pragma("unroll") for (int db = 0; db < 2; ++db)                              \
      _Pragma("unroll") for (int kc = 0; kc < 4; ++kc) {                          \
        bf16x8 va = LDSREAD(c, 2 + b, db * 32 + lq, kc * 16 + hi * 8);            \
        cacc[db] = __builtin_amdgcn_mfma_f32_32x32x16_bf16(va, pf[kc], cacc[db], 0, 0, 0); \
      }                                                                           \
    c ^= 1;                                                                       \
  }

  float4 bvA[2][4], bvB[2][4];
  STAGE(0, 0);
  LOADB(bvA, 0);
  int c = 0;
  for (int t0 = 0; t0 < S_LEN / 64; t0 += 2) {
    BODY(t0, bvA, bvB);
    BODY(t0 + 1, bvB, bvA);
  }
#undef STAGE
#undef LDSREAD
#undef LOADB
#undef BODY

  // ---- epilogue: ctx^T reg (d=db*32+crow(r,hi), q=lane&31) -> ctx[tok][h*64+d] ----
  {
    const float linv = 1.0f / l_run;
    u16* cp = ctx + ((size_t)(b * S_LEN + q0 + lq)) * DM + h * DH;
#pragma unroll
    for (int db = 0; db < 2; ++db)
#pragma unroll
      for (int r = 0; r < 16; ++r)
        cp[db * 32 + (r & 3) + 8 * (r >> 2) + 4 * hi] = f2bf(cacc[db][r] * linv);
  }
}

extern "C" void kernel_launch(void* const* d_in, const int* in_sizes, int n_in,
                              void* d_out, int out_size, void* d_ws, size_t ws_size,
                              hipStream_t stream) {
  const float* q   = (const float*)d_in[0];
  const float* k   = (const float*)d_in[1];
  const float* v   = (const float*)d_in[2];
  const int*   msk = (const int*)d_in[3];
  const float* pb  = (const float*)d_in[4];
  const float* w_q = (const float*)d_in[5];
  const float* b_q = (const float*)d_in[6];
  const float* w_k = (const float*)d_in[7];
  const float* b_k = (const float*)d_in[8];
  const float* w_v = (const float*)d_in[9];
  const float* b_v = (const float*)d_in[10];
  const float* w_o = (const float*)d_in[11];
  const float* b_o = (const float*)d_in[12];
  float* out = (float*)d_out;

  char* ws = (char*)d_ws;
  u16* wq_bf = (u16*)(ws + ((size_t)0 << 20));
  u16* wk_bf = (u16*)(ws + ((size_t)2 << 20));
  u16* wv_bf = (u16*)(ws + ((size_t)4 << 20));
  u16* wo_bf = (u16*)(ws + ((size_t)6 << 20));
  u16* x_bf  = (u16*)(ws + ((size_t)8 << 20));   // staging; reused as ctx
  u16* Qb    = (u16*)(ws + ((size_t)16 << 20));
  u16* Kb    = (u16*)(ws + ((size_t)24 << 20));
  u16* Vtb   = (u16*)(ws + ((size_t)32 << 20));
  u64* mpk   = (u64*)(ws + ((size_t)40 << 20));  // 1 MB packed mask

  dim3 blk(256);
  const int n4w = DM * DM / 4;
  const int n4x = MTOK * DM / 4;
  k_convert<<<dim3(1024), blk, 0, stream>>>(w_q, wq_bf, n4w);
  k_convert<<<dim3(1024), blk, 0, stream>>>(w_k, wk_bf, n4w);
  k_convert<<<dim3(1024), blk, 0, stream>>>(w_v, wv_bf, n4w);
  k_convert<<<dim3(1024), blk, 0, stream>>>(w_o, wo_bf, n4w);
  k_maskpack<<<dim3(2048), blk, 0, stream>>>(msk, mpk, 2 * S_LEN * S_LEN);

  dim3 gg(32, 8);
  k_convert<<<dim3(2048), blk, 0, stream>>>(q, x_bf, n4x);
  k_gemm<0><<<gg, blk, 0, stream>>>(x_bf, wq_bf, b_q, Qb);
  k_convert<<<dim3(2048), blk, 0, stream>>>(k, x_bf, n4x);
  k_gemm<0><<<gg, blk, 0, stream>>>(x_bf, wk_bf, b_k, Kb);
  k_convert<<<dim3(2048), blk, 0, stream>>>(v, x_bf, n4x);
  k_gemm<1><<<gg, blk, 0, stream>>>(x_bf, wv_bf, b_v, Vtb);

  k_attn<<<dim3(32, NH), blk, 0, stream>>>(Qb, Kb, Vtb, pb, mpk, x_bf);
  k_gemm<2><<<gg, blk, 0, stream>>>(x_bf, wo_bf, b_o, out);
}

// Round 8
// 283.690 us; speedup vs baseline: 1.8642x; 1.0132x over previous
//
#include <hip/hip_runtime.h>
#include <hip/hip_bf16.h>

#define S_LEN 2048
#define DM 1024
#define NH 16
#define DH 64
#define MTOK 4096

typedef __attribute__((ext_vector_type(8))) __bf16 bf16x8;
typedef __attribute__((ext_vector_type(4))) float f32x4;
typedef __attribute__((ext_vector_type(16))) float f32x16;
typedef unsigned short u16;
typedef unsigned long long u64;

__device__ __forceinline__ u16 f2bf(float f) {
  union { float f; unsigned u; } a; a.f = f;
  unsigned u = a.u;
  u += 0x7fffu + ((u >> 16) & 1u);   // RNE
  return (u16)(u >> 16);
}

__device__ __forceinline__ bf16x8 ld_bf8(const u16* p) {
  return *reinterpret_cast<const bf16x8*>(p);
}

// ---------------- fp32 -> bf16 convert ----------------
__global__ void k_convert(const float* __restrict__ src, u16* __restrict__ dst, int n4) {
  int i = blockIdx.x * blockDim.x + threadIdx.x;
  int stride = gridDim.x * blockDim.x;
  for (; i < n4; i += stride) {
    float4 v = reinterpret_cast<const float4*>(src)[i];
    ushort4 o;
    o.x = f2bf(v.x); o.y = f2bf(v.y); o.z = f2bf(v.z); o.w = f2bf(v.w);
    reinterpret_cast<ushort4*>(dst)[i] = o;
  }
}

// ---------------- mask bit-pack: [B][S][S] i32 -> [B][S][S/64] u64 ----------------
__global__ void k_maskpack(const int* __restrict__ m, u64* __restrict__ o, int n) {
  int i = blockIdx.x * blockDim.x + threadIdx.x;
  int stride = gridDim.x * blockDim.x;
  for (; i < n; i += stride) {
    u64 bal = __ballot(m[i] != 0);
    if ((i & 63) == 0) o[i >> 6] = bal;
  }
}

// ---------------- bf16 GEMM, B^T weights: C = A @ W^T + bias ----------------
template<int MODE>
__global__ __launch_bounds__(256) void k_gemm(
    const u16* __restrict__ A, const u16* __restrict__ Bw,
    const float* __restrict__ bias, void* __restrict__ dst) {
  constexpr int K = DM;
  __shared__ u16 As[128 * 32];
  __shared__ u16 Bs[128 * 32];
  const int tid = threadIdx.x;
  const int lane = tid & 63;
  const int wid = tid >> 6;
  const int wm = wid >> 1, wn = wid & 1;
  const int bm = blockIdx.x * 128;
  const int bn = blockIdx.y * 128;
  const int r0 = tid >> 2;
  const int c0 = (tid & 3) * 8;
  const int fr = lane & 15;
  const int fk = (lane >> 4) * 8;

  f32x4 acc[4][4] = {};

  const u16* ga = A + (size_t)(bm + r0) * K + c0;
  const u16* gb = Bw + (size_t)(bn + r0) * K + c0;

  for (int kt = 0; kt < K; kt += 32) {
    __syncthreads();
    __builtin_amdgcn_global_load_lds(
        (const __attribute__((address_space(1))) void*)(ga + kt),
        (__attribute__((address_space(3))) void*)(&As[r0 * 32 + c0]), 16, 0, 0);
    __builtin_amdgcn_global_load_lds(
        (const __attribute__((address_space(1))) void*)(ga + (size_t)64 * K + kt),
        (__attribute__((address_space(3))) void*)(&As[(r0 + 64) * 32 + c0]), 16, 0, 0);
    __builtin_amdgcn_global_load_lds(
        (const __attribute__((address_space(1))) void*)(gb + kt),
        (__attribute__((address_space(3))) void*)(&Bs[r0 * 32 + c0]), 16, 0, 0);
    __builtin_amdgcn_global_load_lds(
        (const __attribute__((address_space(1))) void*)(gb + (size_t)64 * K + kt),
        (__attribute__((address_space(3))) void*)(&Bs[(r0 + 64) * 32 + c0]), 16, 0, 0);
    __syncthreads();
    bf16x8 af[4], bfr[4];
#pragma unroll
    for (int m = 0; m < 4; ++m) af[m] = ld_bf8(&As[(wm * 64 + m * 16 + fr) * 32 + fk]);
#pragma unroll
    for (int n = 0; n < 4; ++n) bfr[n] = ld_bf8(&Bs[(wn * 64 + n * 16 + fr) * 32 + fk]);
#pragma unroll
    for (int m = 0; m < 4; ++m)
#pragma unroll
      for (int n = 0; n < 4; ++n)
        acc[m][n] = __builtin_amdgcn_mfma_f32_16x16x32_bf16(af[m], bfr[n], acc[m][n], 0, 0, 0);
  }

  const int cr = (lane >> 4) * 4;
  const int cc = lane & 15;
#pragma unroll
  for (int m = 0; m < 4; ++m) {
#pragma unroll
    for (int n = 0; n < 4; ++n) {
      const int colg = bn + wn * 64 + n * 16 + cc;
      const float bv = bias[colg];
      const int rbase = bm + wm * 64 + m * 16 + cr;
      if (MODE == 2) {
        float* o = (float*)dst;
#pragma unroll
        for (int r = 0; r < 4; ++r)
          o[(size_t)(rbase + r) * DM + colg] = acc[m][n][r] + bv;
      } else if (MODE == 0) {
        u16* o = (u16*)dst;
        const int h = colg >> 6, d = colg & 63;
#pragma unroll
        for (int r = 0; r < 4; ++r) {
          const int tok = rbase + r;
          const int b = tok >> 11, s = tok & 2047;
          o[(((size_t)(b * NH + h) * S_LEN) + s) * DH + d] = f2bf(acc[m][n][r] + bv);
        }
      } else {
        u16* o = (u16*)dst;
        const int h = colg >> 6, d = colg & 63;
        const int tok = rbase;
        const int b = tok >> 11, s = tok & 2047;
        ushort4 pk;
        pk.x = f2bf(acc[m][n][0] + bv);
        pk.y = f2bf(acc[m][n][1] + bv);
        pk.z = f2bf(acc[m][n][2] + bv);
        pk.w = f2bf(acc[m][n][3] + bv);
        *reinterpret_cast<ushort4*>(&o[(((size_t)(b * NH + h) * DH) + d) * S_LEN + s]) = pk;
      }
    }
  }
}

// ---------------- fused flash attention ----------------
// 4 waves = (qsub, batch): wave w -> b = w>>1, q0 = blk*64 + (w&1)*32.
// Counted-vmcnt barrier (T4): issue order pinned {STAGE 8 gload_lds} |
// sched_barrier | {8 bias float4 + 1 mask u64}; at the next barrier
// "s_waitcnt vmcnt(9)" drains exactly the stage group, bias/mask prefetches
// stay in flight across the barrier. lgkmcnt(0) preserves dbuf read-before-
// overwrite. s_setprio(1) around both MFMA clusters (T5).
__global__ __launch_bounds__(256, 2) void k_attn(
    const u16* __restrict__ Qb, const u16* __restrict__ Kb, const u16* __restrict__ Vt,
    const float* __restrict__ bias, const u64* __restrict__ mpk,
    u16* __restrict__ ctx) {
  __shared__ u16 lds[2][4][4096];   // [buf][K b0, K b1, V b0, V b1][64*64]
  const int tid = threadIdx.x;
  const int lane = tid & 63;
  const int w = tid >> 6;
  const int b = w >> 1;
  const int h = blockIdx.y;
  const int q0 = blockIdx.x * 64 + (w & 1) * 32;
  const int lq = lane & 31;
  const int hi = lane >> 5;

  const float* bp = bias + (size_t)h * S_LEN * S_LEN;

  bf16x8 qf[4];
  f32x16 cacc[2] = {};
  float m_run = -1e30f, l_run = 0.f;
  {
    const u16* Qp = Qb + (size_t)(b * NH + h) * S_LEN * DH;
#pragma unroll
    for (int d0 = 0; d0 < 4; ++d0)
      qf[d0] = ld_bf8(&Qp[(size_t)(q0 + lq) * DH + d0 * 16 + hi * 8]);
  }

#define STAGE(ktv, cb) {                                                          \
    _Pragma("unroll") for (int i = 0; i < 2; ++i) {                               \
      const int el = (i * 256 + tid) * 8;                                         \
      const int rr = el >> 6;                                                     \
      const int ce = ((tid & 7) * 8) ^ ((rr & 7) << 3);                           \
      _Pragma("unroll") for (int b2 = 0; b2 < 2; ++b2) {                          \
        const u16* ksrc = Kb + (size_t)(b2 * NH + h) * S_LEN * DH                 \
                          + (size_t)((ktv) + rr) * DH + ce;                       \
        const u16* vsrc = Vt + (size_t)(b2 * NH + h) * DH * S_LEN                 \
                          + (size_t)rr * S_LEN + (ktv) + ce;                      \
        __builtin_amdgcn_global_load_lds(                                         \
            (const __attribute__((address_space(1))) void*)ksrc,                  \
            (__attribute__((address_space(3))) void*)&lds[cb][b2][el], 16, 0, 0); \
        __builtin_amdgcn_global_load_lds(                                         \
            (const __attribute__((address_space(1))) void*)vsrc,                  \
            (__attribute__((address_space(3))) void*)&lds[cb][2 + b2][el], 16, 0, 0); \
      } } }

#define LDSREAD(cb, tile, row, cel) \
    ld_bf8(&lds[cb][tile][(row) * 64 + (((cel)) ^ (((row) & 7) << 3))])

#define LOADB(BV, ktv) {                                                          \
    _Pragma("unroll") for (int kb = 0; kb < 2; ++kb)                              \
      _Pragma("unroll") for (int rq = 0; rq < 4; ++rq)                            \
        BV[kb][rq] = *reinterpret_cast<const float4*>(                            \
            &bp[(size_t)(q0 + lq) * S_LEN + (ktv) + kb * 32 + rq * 8 + hi * 4]); }

// counted-vmcnt barrier: drain stage group (oldest), keep bias/mask in flight
#define BARRIER() {                                                               \
    asm volatile("s_waitcnt vmcnt(9) lgkmcnt(0)" ::: "memory");                   \
    __builtin_amdgcn_sched_barrier(0);                                            \
    __builtin_amdgcn_s_barrier();                                                 \
    __builtin_amdgcn_sched_barrier(0); }

#define BODY(T, BV, MW, BVN, MWN) {                                               \
    const int ktv = (T) * 64;                                                     \
    BARRIER();                                                                    \
    if ((T) + 1 < S_LEN / 64) {                                                   \
      STAGE(ktv + 64, c ^ 1);                                                     \
      __builtin_amdgcn_sched_barrier(0);                                          \
      LOADB(BVN, ktv + 64);                                                       \
      MWN = mpk[((size_t)(b * S_LEN + q0 + lq)) * 32 + (ktv >> 6) + 1];           \
    }                                                                             \
    f32x16 sc0 = {}, sc1 = {};                                                    \
    __builtin_amdgcn_s_setprio(1);                                                \
    _Pragma("unroll") for (int d0 = 0; d0 < 4; ++d0) {                            \
      bf16x8 ka0 = LDSREAD(c, b, lq, d0 * 16 + hi * 8);                           \
      sc0 = __builtin_amdgcn_mfma_f32_32x32x16_bf16(ka0, qf[d0], sc0, 0, 0, 0);   \
      bf16x8 ka1 = LDSREAD(c, b, 32 + lq, d0 * 16 + hi * 8);                      \
      sc1 = __builtin_amdgcn_mfma_f32_32x32x16_bf16(ka1, qf[d0], sc1, 0, 0, 0);   \
    }                                                                             \
    __builtin_amdgcn_s_setprio(0);                                                \
    _Pragma("unroll") for (int r = 0; r < 16; ++r) {                              \
      const int cr_ = (r & 3) + 8 * (r >> 2);                                     \
      const float v0_ = sc0[r] * 0.125f + ((const float*)&BV[0][r >> 2])[r & 3];  \
      sc0[r] = ((MW >> (cr_ + 4 * hi)) & 1) ? v0_ : -1e9f;                        \
      const float v1_ = sc1[r] * 0.125f + ((const float*)&BV[1][r >> 2])[r & 3];  \
      sc1[r] = ((MW >> (32 + cr_ + 4 * hi)) & 1) ? v1_ : -1e9f;                   \
    }                                                                             \
    float vm = fmaxf(sc0[0], sc1[0]);                                             \
    _Pragma("unroll") for (int r = 1; r < 16; ++r)                                \
      vm = fmaxf(vm, fmaxf(sc0[r], sc1[r]));                                      \
    vm = fmaxf(vm, __shfl_xor(vm, 32));                                           \
    if (!__all(vm <= m_run)) {                                                    \
      const float mn = fmaxf(m_run, vm);                                          \
      const float corr = __expf(m_run - mn);                                      \
      m_run = mn;                                                                 \
      l_run *= corr;                                                              \
      _Pragma("unroll") for (int r = 0; r < 16; ++r) {                            \
        cacc[0][r] *= corr; cacc[1][r] *= corr; }                                 \
    }                                                                             \
    float ssum = 0.f;                                                             \
    _Pragma("unroll") for (int r = 0; r < 16; ++r) {                              \
      const float p0 = __expf(sc0[r] - m_run); sc0[r] = p0;                       \
      const float p1 = __expf(sc1[r] - m_run); sc1[r] = p1;                       \
      ssum += p0 + p1;                                                            \
    }                                                                             \
    ssum += __shfl_xor(ssum, 32);                                                 \
    l_run += ssum;                                                                \
    unsigned pw0[8], pw1[8];                                                      \
    _Pragma("unroll") for (int i2 = 0; i2 < 8; ++i2) {                            \
      pw0[i2] = (unsigned)f2bf(sc0[2 * i2]) | ((unsigned)f2bf(sc0[2 * i2 + 1]) << 16); \
      pw1[i2] = (unsigned)f2bf(sc1[2 * i2]) | ((unsigned)f2bf(sc1[2 * i2 + 1]) << 16); \
    }                                                                             \
    bf16x8 pf[4];                                                                 \
    _Pragma("unroll") for (int kb = 0; kb < 2; ++kb)                              \
      _Pragma("unroll") for (int ch = 0; ch < 2; ++ch) {                          \
        const unsigned a0 = kb ? pw1[ch * 4 + 0] : pw0[ch * 4 + 0];               \
        const unsigned a1 = kb ? pw1[ch * 4 + 1] : pw0[ch * 4 + 1];               \
        const unsigned a2 = kb ? pw1[ch * 4 + 2] : pw0[ch * 4 + 2];               \
        const unsigned a3 = kb ? pw1[ch * 4 + 3] : pw0[ch * 4 + 3];               \
        const unsigned sx0 = __shfl_xor(a0, 32), sx1 = __shfl_xor(a1, 32);        \
        const unsigned sx2 = __shfl_xor(a2, 32), sx3 = __shfl_xor(a3, 32);        \
        union { unsigned u[4]; bf16x8 v; } f;                                     \
        f.u[0] = hi ? sx2 : a0;                                                   \
        f.u[1] = hi ? sx3 : a1;                                                   \
        f.u[2] = hi ? a2 : sx0;                                                   \
        f.u[3] = hi ? a3 : sx1;                                                   \
        pf[kb * 2 + ch] = f.v;                                                    \
      }                                                                           \
    __builtin_amdgcn_s_setprio(1);                                                \
    _Pragma("unroll") for (int db = 0; db < 2; ++db)                              \
      _Pragma("unroll") for (int kc = 0; kc < 4; ++kc) {                          \
        bf16x8 va = LDSREAD(c, 2 + b, db * 32 + lq, kc * 16 + hi * 8);            \
        cacc[db] = __builtin_amdgcn_mfma_f32_32x32x16_bf16(va, pf[kc], cacc[db], 0, 0, 0); \
      }                                                                           \
    __builtin_amdgcn_s_setprio(0);                                                \
    c ^= 1;                                                                       \
  }

  float4 bvA[2][4], bvB[2][4];
  u64 mwA, mwB;
  STAGE(0, 0);
  __builtin_amdgcn_sched_barrier(0);
  LOADB(bvA, 0);
  mwA = mpk[((size_t)(b * S_LEN + q0 + lq)) * 32];
  int c = 0;
  for (int t0 = 0; t0 < S_LEN / 64; t0 += 2) {
    BODY(t0, bvA, mwA, bvB, mwB);
    BODY(t0 + 1, bvB, mwB, bvA, mwA);
  }
#undef STAGE
#undef LDSREAD
#undef LOADB
#undef BARRIER
#undef BODY

  // ---- epilogue ----
  {
    const float linv = 1.0f / l_run;
    u16* cp = ctx + ((size_t)(b * S_LEN + q0 + lq)) * DM + h * DH;
#pragma unroll
    for (int db = 0; db < 2; ++db)
#pragma unroll
      for (int r = 0; r < 16; ++r)
        cp[db * 32 + (r & 3) + 8 * (r >> 2) + 4 * hi] = f2bf(cacc[db][r] * linv);
  }
}

extern "C" void kernel_launch(void* const* d_in, const int* in_sizes, int n_in,
                              void* d_out, int out_size, void* d_ws, size_t ws_size,
                              hipStream_t stream) {
  const float* q   = (const float*)d_in[0];
  const float* k   = (const float*)d_in[1];
  const float* v   = (const float*)d_in[2];
  const int*   msk = (const int*)d_in[3];
  const float* pb  = (const float*)d_in[4];
  const float* w_q = (const float*)d_in[5];
  const float* b_q = (const float*)d_in[6];
  const float* w_k = (const float*)d_in[7];
  const float* b_k = (const float*)d_in[8];
  const float* w_v = (const float*)d_in[9];
  const float* b_v = (const float*)d_in[10];
  const float* w_o = (const float*)d_in[11];
  const float* b_o = (const float*)d_in[12];
  float* out = (float*)d_out;

  char* ws = (char*)d_ws;
  u16* wq_bf = (u16*)(ws + ((size_t)0 << 20));
  u16* wk_bf = (u16*)(ws + ((size_t)2 << 20));
  u16* wv_bf = (u16*)(ws + ((size_t)4 << 20));
  u16* wo_bf = (u16*)(ws + ((size_t)6 << 20));
  u16* x_bf  = (u16*)(ws + ((size_t)8 << 20));   // staging; reused as ctx
  u16* Qb    = (u16*)(ws + ((size_t)16 << 20));
  u16* Kb    = (u16*)(ws + ((size_t)24 << 20));
  u16* Vtb   = (u16*)(ws + ((size_t)32 << 20));
  u64* mpk   = (u64*)(ws + ((size_t)40 << 20));  // 1 MB packed mask

  dim3 blk(256);
  const int n4w = DM * DM / 4;
  const int n4x = MTOK * DM / 4;
  k_convert<<<dim3(1024), blk, 0, stream>>>(w_q, wq_bf, n4w);
  k_convert<<<dim3(1024), blk, 0, stream>>>(w_k, wk_bf, n4w);
  k_convert<<<dim3(1024), blk, 0, stream>>>(w_v, wv_bf, n4w);
  k_convert<<<dim3(1024), blk, 0, stream>>>(w_o, wo_bf, n4w);
  k_maskpack<<<dim3(2048), blk, 0, stream>>>(msk, mpk, 2 * S_LEN * S_LEN);

  dim3 gg(32, 8);
  k_convert<<<dim3(2048), blk, 0, stream>>>(q, x_bf, n4x);
  k_gemm<0><<<gg, blk, 0, stream>>>(x_bf, wq_bf, b_q, Qb);
  k_convert<<<dim3(2048), blk, 0, stream>>>(k, x_bf, n4x);
  k_gemm<0><<<gg, blk, 0, stream>>>(x_bf, wk_bf, b_k, Kb);
  k_convert<<<dim3(2048), blk, 0, stream>>>(v, x_bf, n4x);
  k_gemm<1><<<gg, blk, 0, stream>>>(x_bf, wv_bf, b_v, Vtb);

  k_attn<<<dim3(32, NH), blk, 0, stream>>>(Qb, Kb, Vtb, pb, mpk, x_bf);
  k_gemm<2><<<gg, blk, 0, stream>>>(x_bf, wo_bf, b_o, out);
}